// Round 6
// baseline (279.001 us; speedup 1.0000x reference)
//
#include <hip/hip_runtime.h>

typedef short short8 __attribute__((ext_vector_type(8)));
typedef _Float16 half8 __attribute__((ext_vector_type(8)));
typedef _Float16 half4 __attribute__((ext_vector_type(4)));
typedef float f32x4 __attribute__((ext_vector_type(4)));

// bf16 bit helpers (RNE)
__device__ __forceinline__ short f2bf(float f) {
    union { float f; unsigned u; } c; c.f = f;
    unsigned r = c.u + 0x7fffu + ((c.u >> 16) & 1u);
    return (short)(r >> 16);
}
__device__ __forceinline__ float bf2f(short s) {
    union { unsigned u; float f; } c; c.u = ((unsigned)(unsigned short)s) << 16;
    return c.f;
}

__device__ __forceinline__ void glds16(const void* g, void* l) {
    __builtin_amdgcn_global_load_lds(
        (const __attribute__((address_space(1))) unsigned int*)g,
        (__attribute__((address_space(3))) unsigned int*)l, 16, 0, 0);
}

// ---------------------------------------------------------------------------
// Sizes: B=8, C=512, H=8, D=64, N=1024, proj M=K=1536 (3C rows / split-K cols)
// ---------------------------------------------------------------------------

// Pack Wq/Wk/Wv into A2[1536][1536] = [Whi | Whi | Wlo] rows, plus bias2[1536].
__global__ void k_pack_w(const float* __restrict__ Wq, const float* __restrict__ Wk,
                         const float* __restrict__ Wv, const float* __restrict__ bq,
                         const float* __restrict__ bk, const float* __restrict__ bv,
                         short* __restrict__ A2, float* __restrict__ bias2) {
    int t = blockIdx.x * 256 + threadIdx.x;      // 98304 threads
    int m = t >> 6;
    int c8 = (t & 63) << 3;
    const float* src = (m < 512) ? (Wq + m * 512)
                     : (m < 1024 ? (Wk + (m - 512) * 512) : (Wv + (m - 1024) * 512));
    float4 v0 = *(const float4*)(src + c8);
    float4 v1 = *(const float4*)(src + c8 + 4);
    float f[8] = {v0.x, v0.y, v0.z, v0.w, v1.x, v1.y, v1.z, v1.w};
    short8 hi, lo;
#pragma unroll
    for (int j = 0; j < 8; ++j) {
        short h = f2bf(f[j]);
        hi[j] = h;
        lo[j] = f2bf(f[j] - bf2f(h));
    }
    short* rowp = A2 + (size_t)m * 1536;
    *(short8*)(rowp + c8)        = hi;
    *(short8*)(rowp + 512 + c8)  = hi;
    *(short8*)(rowp + 1024 + c8) = lo;
    if (t < 1536)
        bias2[t] = (t < 512) ? bq[t] : (t < 1024 ? bk[t - 512] : bv[t - 1024]);
}

// Transpose x[b][c][n] -> xT2[b][n][1536] = [xhi | xlo | xhi] (k-contiguous rows)
__global__ void k_prep_x(const float* __restrict__ x, short* __restrict__ xT2) {
    __shared__ float xs[64][65];
    int nt = blockIdx.x * 64, ct = blockIdx.y * 64, b = blockIdx.z;
    int t = threadIdx.x;
    const float* xb = x + ((size_t)b * 512 + ct) * 1024 + nt;
#pragma unroll
    for (int p = 0; p < 4; ++p) {
        int c = p * 16 + (t >> 4), n4 = (t & 15) * 4;
        float4 v = *(const float4*)(xb + (size_t)c * 1024 + n4);
        xs[c][n4] = v.x; xs[c][n4 + 1] = v.y; xs[c][n4 + 2] = v.z; xs[c][n4 + 3] = v.w;
    }
    __syncthreads();
    int nl = t >> 2, part = t & 3;
    short* rowp = xT2 + ((size_t)b * 1024 + nt + nl) * 1536;
#pragma unroll
    for (int g = 0; g < 2; ++g) {
        short8 hi, lo;
#pragma unroll
        for (int j = 0; j < 8; ++j) {
            float f = xs[part * 16 + g * 8 + j][nl];
            short h = f2bf(f);
            hi[j] = h; lo[j] = f2bf(f - bf2f(h));
        }
        int c = ct + part * 16 + g * 8;
        *(short8*)(rowp + c)        = hi;
        *(short8*)(rowp + 512 + c)  = lo;
        *(short8*)(rowp + 1024 + c) = hi;
    }
}

// rel2[h][n][64] fp16
__global__ void k_prep_rel(const float* __restrict__ rel_h, const float* __restrict__ rel_w,
                           _Float16* __restrict__ rel2) {
    int tid = blockIdx.x * 256 + threadIdx.x;   // 65536
    int h = tid >> 13;
    int rem = tid & 8191;
    int n = rem >> 3;
    int g = rem & 7;
    int hh = n & 31, ww = n >> 5;
    half8 o;
#pragma unroll
    for (int j = 0; j < 8; ++j) {
        int d = g * 8 + j;
        o[j] = (_Float16)(rel_h[(h * 64 + d) * 32 + hh] + rel_w[(h * 64 + d) * 32 + ww]);
    }
    *(half8*)(rel2 + ((size_t)h * 1024 + n) * 64 + g * 8) = o;
}

// Split-bf16 GEMM, BK=64 (two R5-swizzled 32-K sub-tiles per LDS buffer).
// glds16 staging; fused epilogue writes q2/k2 ([bh][n][d]) and vb ([bh][d][n]).
__global__ __launch_bounds__(256, 3) void k_proj(const short* __restrict__ A2,
                                                 const short* __restrict__ xT2,
                                                 const float* __restrict__ bias2,
                                                 _Float16* __restrict__ q2,
                                                 _Float16* __restrict__ k2,
                                                 _Float16* __restrict__ vb) {
    __shared__ __align__(16) short As[8192];   // [2 kh][128 rows][32 shorts], swizzled
    __shared__ __align__(16) short Bs[8192];
    int t = threadIdx.x;
    int lane = t & 63, w = t >> 6;
    int lm = lane & 15, lq = lane >> 4;
    int wr = (w >> 1) * 64, wc = (w & 1) * 64;
    int mb = blockIdx.y * 128, nb = blockIdx.x * 128, b = blockIdx.z;
    int rl = lane >> 2;                                   // row within 16-row group
    int csw = ((lane & 3) ^ ((lane >> 3) & 3)) * 8;       // swizzled col (shorts)
    const short* Ag0 = A2 + (size_t)(mb + w * 32 + rl) * 1536 + csw;
    const short* Ag1 = Ag0 + 16 * 1536;
    const short* Bg0 = xT2 + ((size_t)b * 1024 + nb + w * 32 + rl) * 1536 + csw;
    const short* Bg1 = Bg0 + 16 * 1536;
    f32x4 acc[4][4];
#pragma unroll
    for (int i = 0; i < 4; ++i)
#pragma unroll
        for (int j = 0; j < 4; ++j) acc[i][j] = {0.f, 0.f, 0.f, 0.f};
    int fsw = (lq ^ ((lm >> 1) & 3)) * 8;                 // fragment-read swizzle
    for (int k0 = 0; k0 < 1536; k0 += 64) {
#pragma unroll
        for (int kh = 0; kh < 2; ++kh) {
            int ko = k0 + kh * 32;
            glds16(Ag0 + ko, &As[kh * 4096 + (w * 32) * 32]);
            glds16(Ag1 + ko, &As[kh * 4096 + (w * 32 + 16) * 32]);
            glds16(Bg0 + ko, &Bs[kh * 4096 + (w * 32) * 32]);
            glds16(Bg1 + ko, &Bs[kh * 4096 + (w * 32 + 16) * 32]);
        }
        __syncthreads();
#pragma unroll
        for (int kh = 0; kh < 2; ++kh) {
            short8 af[4], bfr[4];
#pragma unroll
            for (int mt = 0; mt < 4; ++mt)
                af[mt] = *(short8*)&As[kh * 4096 + (wr + mt * 16 + lm) * 32 + fsw];
#pragma unroll
            for (int nt = 0; nt < 4; ++nt)
                bfr[nt] = *(short8*)&Bs[kh * 4096 + (wc + nt * 16 + lm) * 32 + fsw];
#pragma unroll
            for (int mt = 0; mt < 4; ++mt)
#pragma unroll
                for (int nt = 0; nt < 4; ++nt)
                    acc[mt][nt] = __builtin_amdgcn_mfma_f32_16x16x32_bf16(af[mt], bfr[nt], acc[mt][nt], 0, 0, 0);
        }
        __syncthreads();
    }
    // Epilogue: section 0=q (rows 0-511), 1=k, 2=v; head-aligned since (mb+wr)%64==0
    int sect = mb >> 9;
    int hloc = ((mb & 511) + wr) >> 6;
    size_t bh = (size_t)b * 8 + hloc;
    if (sect < 2) {
        _Float16* dst = (sect == 0 ? q2 : k2) + bh * 1024 * 64;
#pragma unroll
        for (int mt = 0; mt < 4; ++mt) {
            int d0 = mt * 16 + lq * 4;
            float bi0 = bias2[mb + wr + d0];
            float bi1 = bias2[mb + wr + d0 + 1];
            float bi2 = bias2[mb + wr + d0 + 2];
            float bi3 = bias2[mb + wr + d0 + 3];
#pragma unroll
            for (int nt = 0; nt < 4; ++nt) {
                int n = nb + wc + nt * 16 + lm;
                half4 o;
                o[0] = (_Float16)(acc[mt][nt][0] + bi0);
                o[1] = (_Float16)(acc[mt][nt][1] + bi1);
                o[2] = (_Float16)(acc[mt][nt][2] + bi2);
                o[3] = (_Float16)(acc[mt][nt][3] + bi3);
                *(half4*)(dst + (size_t)n * 64 + d0) = o;
            }
        }
    } else {
        _Float16* dst = vb + bh * 64 * 1024;
#pragma unroll
        for (int mt = 0; mt < 4; ++mt)
#pragma unroll
            for (int reg = 0; reg < 4; ++reg) {
                int d = mt * 16 + lq * 4 + reg;
                float bi = bias2[mb + wr + d];
#pragma unroll
                for (int nt = 0; nt < 4; ++nt) {
                    int n = nb + wc + nt * 16 + lm;
                    dst[(size_t)d * 1024 + n] = (_Float16)(acc[mt][nt][reg] + bi);
                }
            }
    }
}

// Flash attention, fp16, S^T orientation, register-prefetched staging.
__global__ __launch_bounds__(256, 4) void k_attn(const _Float16* __restrict__ q2,
                                                 const _Float16* __restrict__ k2,
                                                 const _Float16* __restrict__ rel2,
                                                 const _Float16* __restrict__ vb,
                                                 float* __restrict__ out) {
    __shared__ __align__(16) char pool[35840];
    _Float16* kb_s = (_Float16*)pool;            // [64][136] = 17408 B (phase-0: qa rows)
    _Float16* v_s  = (_Float16*)(pool + 17408);  // [64][72]  =  9216 B
    _Float16* p_s  = (_Float16*)(pool + 26624);  // [64 m][72 n] = 9216 B (wave-private rows)
    int t = threadIdx.x;
    int lane = t & 63, w = t >> 6;
    int lm = lane & 15, lq = lane >> 4;
    int mt0 = blockIdx.x, h = blockIdx.y, b = blockIdx.z;
    size_t bh = (size_t)b * 8 + h;
    const _Float16* q2b = q2 + bh * 1024 * 64;
    const _Float16* k2b = k2 + bh * 1024 * 64;
    const _Float16* relb = rel2 + (size_t)h * 1024 * 64;
    const _Float16* vbb = vb + bh * 64 * 1024;
    float* outb = out + bh * 64 * 1024 + mt0 * 64;

    int r = t >> 2, part = t & 3;
    const _Float16* ksrc = ((part < 2) ? (k2b + part * 32) : (q2b + (part - 2) * 32));
    int vc = (t & 3) * 16;
    const _Float16* vsrcb = vbb + (size_t)r * 1024 + vc;
    _Float16* kdst = kb_s + r * 136 + part * 32;
    _Float16* vdst = v_s + r * 72 + vc;

    // prefetch tile 0 into registers
    uint4 kc[4], vv[2];
    {
        const uint4* s_ = (const uint4*)(ksrc + (size_t)r * 64);
        kc[0] = s_[0]; kc[1] = s_[1]; kc[2] = s_[2]; kc[3] = s_[3];
        const uint4* v_ = (const uint4*)vsrcb;
        vv[0] = v_[0]; vv[1] = v_[1];
    }

    // Phase 0: stage A-side rows [q | rel] for m = mt0*64 .. +63 (aliases kb_s)
    {
        int n = mt0 * 64 + r;
        const _Float16* src = (part < 2) ? (q2b + (size_t)n * 64 + part * 32)
                                         : (relb + (size_t)n * 64 + (part - 2) * 32);
        ((uint4*)kdst)[0] = ((const uint4*)src)[0];
        ((uint4*)kdst)[1] = ((const uint4*)src)[1];
        ((uint4*)kdst)[2] = ((const uint4*)src)[2];
        ((uint4*)kdst)[3] = ((const uint4*)src)[3];
    }
    __syncthreads();
    // q fragment as MFMA *B* operand: col=lm -> m = w*16+lm, k = kk*32 + lq*8 + j
    half8 ah[4];
#pragma unroll
    for (int kk = 0; kk < 4; ++kk)
        ah[kk] = *(half8*)&kb_s[(w * 16 + lm) * 136 + kk * 32 + lq * 8];
    f32x4 acco[4];
#pragma unroll
    for (int i = 0; i < 4; ++i) acco[i] = {0.f, 0.f, 0.f, 0.f};
    float mrun = -3e38f, lrun = 0.f;

    for (int kt = 0; kt < 16; ++kt) {
        __syncthreads();  // prior QK/PV reads of kb_s/v_s done block-wide
        ((uint4*)kdst)[0] = kc[0];
        ((uint4*)kdst)[1] = kc[1];
        ((uint4*)kdst)[2] = kc[2];
        ((uint4*)kdst)[3] = kc[3];
        ((uint4*)vdst)[0] = vv[0];
        ((uint4*)vdst)[1] = vv[1];
        __syncthreads();
        // issue next tile's global loads; vmcnt consumed only at next ds_write
        uint4 kn[4], vn[2];
        if (kt < 15) {
            int n0n = (kt + 1) * 64;
            const uint4* s_ = (const uint4*)(ksrc + (size_t)(n0n + r) * 64);
            kn[0] = s_[0]; kn[1] = s_[1]; kn[2] = s_[2]; kn[3] = s_[3];
            const uint4* v_ = (const uint4*)(vsrcb + n0n);
            vn[0] = v_[0]; vn[1] = v_[1];
        }
        // S^T[n][m]: sac[ct][reg] -> n = ct*16 + lq*4 + reg, m = w*16 + lm
        f32x4 sac[4];
#pragma unroll
        for (int ct = 0; ct < 4; ++ct) sac[ct] = {0.f, 0.f, 0.f, 0.f};
#pragma unroll
        for (int ct = 0; ct < 4; ++ct) {
            half8 kf[4];
#pragma unroll
            for (int kk = 0; kk < 4; ++kk)
                kf[kk] = *(half8*)&kb_s[(ct * 16 + lm) * 136 + kk * 32 + lq * 8];
#pragma unroll
            for (int kk = 0; kk < 4; ++kk)
                sac[ct] = __builtin_amdgcn_mfma_f32_16x16x32_f16(kf[kk], ah[kk], sac[ct], 0, 0, 0);
        }
        // online softmax over n for column m (per-lane; lq-replicated via 2 shuffles)
        float mx = -3e38f;
#pragma unroll
        for (int ct = 0; ct < 4; ++ct)
#pragma unroll
            for (int reg = 0; reg < 4; ++reg) mx = fmaxf(mx, sac[ct][reg]);
        mx = fmaxf(mx, __shfl_xor(mx, 16));
        mx = fmaxf(mx, __shfl_xor(mx, 32));
        float mnew = fmaxf(mrun, mx);
        float al_ = __expf(mrun - mnew);
        float ps[4][4];
        float rs = 0.f;
#pragma unroll
        for (int ct = 0; ct < 4; ++ct)
#pragma unroll
            for (int reg = 0; reg < 4; ++reg) {
                float p = __expf(sac[ct][reg] - mnew);
                ps[ct][reg] = p;
                rs += p;
            }
        rs += __shfl_xor(rs, 16);
        rs += __shfl_xor(rs, 32);
        lrun = lrun * al_ + rs;
        mrun = mnew;
#pragma unroll
        for (int dt = 0; dt < 4; ++dt) {
            acco[dt][0] *= al_; acco[dt][1] *= al_;
            acco[dt][2] *= al_; acco[dt][3] *= al_;
        }
        // store P rows [m][n] (wave-private rows m = w*16 + 0..15): b64 per ct
#pragma unroll
        for (int ct = 0; ct < 4; ++ct) {
            half4 o;
            o[0] = (_Float16)ps[ct][0]; o[1] = (_Float16)ps[ct][1];
            o[2] = (_Float16)ps[ct][2]; o[3] = (_Float16)ps[ct][3];
            *(half4*)&p_s[(w * 16 + lm) * 72 + ct * 16 + lq * 4] = o;
        }
        // PV: out^T[d][m] += v[d][n] * P^T[n][m]
        half8 pfr[2];
#pragma unroll
        for (int ch = 0; ch < 2; ++ch)
            pfr[ch] = *(half8*)&p_s[(w * 16 + lm) * 72 + ch * 32 + lq * 8];
#pragma unroll
        for (int dt = 0; dt < 4; ++dt) {
            half8 vf0 = *(half8*)&v_s[(dt * 16 + lm) * 72 + lq * 8];
            half8 vf1 = *(half8*)&v_s[(dt * 16 + lm) * 72 + 32 + lq * 8];
            acco[dt] = __builtin_amdgcn_mfma_f32_16x16x32_f16(vf0, pfr[0], acco[dt], 0, 0, 0);
            acco[dt] = __builtin_amdgcn_mfma_f32_16x16x32_f16(vf1, pfr[1], acco[dt], 0, 0, 0);
        }
        // rotate prefetched registers into current
        kc[0] = kn[0]; kc[1] = kn[1]; kc[2] = kn[2]; kc[3] = kn[3];
        vv[0] = vn[0]; vv[1] = vn[1];
    }
    float li = 1.f / lrun;
#pragma unroll
    for (int dt = 0; dt < 4; ++dt)
#pragma unroll
        for (int reg = 0; reg < 4; ++reg) {
            int d = dt * 16 + lq * 4 + reg;
            outb[(size_t)d * 1024 + w * 16 + lm] = acco[dt][reg] * li;
        }
}

extern "C" void kernel_launch(void* const* d_in, const int* in_sizes, int n_in,
                              void* d_out, int out_size, void* d_ws, size_t ws_size,
                              hipStream_t stream) {
    const float* x     = (const float*)d_in[0];
    const float* Wq    = (const float*)d_in[1];
    const float* bq    = (const float*)d_in[2];
    const float* Wk    = (const float*)d_in[3];
    const float* bk    = (const float*)d_in[4];
    const float* Wv    = (const float*)d_in[5];
    const float* bv    = (const float*)d_in[6];
    const float* rel_h = (const float*)d_in[7];
    const float* rel_w = (const float*)d_in[8];
    char* ws = (char*)d_ws;
    short* A2      = (short*)(ws);                  //  4,718,592 B
    float* bias2   = (float*)(ws + 4718592);        //      6,144 B -> 4,724,736
    short* xT2     = (short*)(ws + 4724736);        // 25,165,824 B -> 29,890,560
    _Float16* q2   = (_Float16*)(ws + 29890560);    //  8,388,608 B -> 38,279,168
    _Float16* k2   = (_Float16*)(ws + 38279168);    //  8,388,608 B -> 46,667,776
    _Float16* vb   = (_Float16*)(ws + 46667776);    //  8,388,608 B -> 55,056,384
    _Float16* rel2 = (_Float16*)(ws + 55056384);    //  1,048,576 B -> 56,104,960
    float* out = (float*)d_out;

    hipLaunchKernelGGL(k_pack_w,   dim3(384),      dim3(256), 0, stream, Wq, Wk, Wv, bq, bk, bv, A2, bias2);
    hipLaunchKernelGGL(k_prep_x,   dim3(16, 8, 8), dim3(256), 0, stream, x, xT2);
    hipLaunchKernelGGL(k_prep_rel, dim3(256),      dim3(256), 0, stream, rel_h, rel_w, rel2);
    hipLaunchKernelGGL(k_proj,     dim3(8, 12, 8), dim3(256), 0, stream, A2, xT2, bias2, q2, k2, vb);
    hipLaunchKernelGGL(k_attn,     dim3(16, 8, 8), dim3(256), 0, stream, q2, k2, rel2, vb, out);
}

// Round 7
// 191.586 us; speedup vs baseline: 1.4563x; 1.4563x over previous
//
#include <hip/hip_runtime.h>

typedef short short8 __attribute__((ext_vector_type(8)));
typedef _Float16 half8 __attribute__((ext_vector_type(8)));
typedef _Float16 half4 __attribute__((ext_vector_type(4)));
typedef float f32x4 __attribute__((ext_vector_type(4)));

// bf16 bit helpers (RNE)
__device__ __forceinline__ short f2bf(float f) {
    union { float f; unsigned u; } c; c.f = f;
    unsigned r = c.u + 0x7fffu + ((c.u >> 16) & 1u);
    return (short)(r >> 16);
}
__device__ __forceinline__ float bf2f(short s) {
    union { unsigned u; float f; } c; c.u = ((unsigned)(unsigned short)s) << 16;
    return c.f;
}

__device__ __forceinline__ void glds16(const void* g, void* l) {
    __builtin_amdgcn_global_load_lds(
        (const __attribute__((address_space(1))) unsigned int*)g,
        (__attribute__((address_space(3))) unsigned int*)l, 16, 0, 0);
}

// ---------------------------------------------------------------------------
// Sizes: B=8, C=512, H=8, D=64, N=1024, proj M=K=1536 (3C rows / split-K cols)
// ---------------------------------------------------------------------------

// Pack Wq/Wk/Wv into A2[1536][1536] = [Whi | Whi | Wlo] rows, plus bias2[1536].
__global__ void k_pack_w(const float* __restrict__ Wq, const float* __restrict__ Wk,
                         const float* __restrict__ Wv, const float* __restrict__ bq,
                         const float* __restrict__ bk, const float* __restrict__ bv,
                         short* __restrict__ A2, float* __restrict__ bias2) {
    int t = blockIdx.x * 256 + threadIdx.x;      // 98304 threads
    int m = t >> 6;
    int c8 = (t & 63) << 3;
    const float* src = (m < 512) ? (Wq + m * 512)
                     : (m < 1024 ? (Wk + (m - 512) * 512) : (Wv + (m - 1024) * 512));
    float4 v0 = *(const float4*)(src + c8);
    float4 v1 = *(const float4*)(src + c8 + 4);
    float f[8] = {v0.x, v0.y, v0.z, v0.w, v1.x, v1.y, v1.z, v1.w};
    short8 hi, lo;
#pragma unroll
    for (int j = 0; j < 8; ++j) {
        short h = f2bf(f[j]);
        hi[j] = h;
        lo[j] = f2bf(f[j] - bf2f(h));
    }
    short* rowp = A2 + (size_t)m * 1536;
    *(short8*)(rowp + c8)        = hi;
    *(short8*)(rowp + 512 + c8)  = hi;
    *(short8*)(rowp + 1024 + c8) = lo;
    if (t < 1536)
        bias2[t] = (t < 512) ? bq[t] : (t < 1024 ? bk[t - 512] : bv[t - 1024]);
}

// Transpose x[b][c][n] -> xT2[b][n][1536] = [xhi | xlo | xhi] (k-contiguous rows)
__global__ void k_prep_x(const float* __restrict__ x, short* __restrict__ xT2) {
    __shared__ float xs[64][65];
    int nt = blockIdx.x * 64, ct = blockIdx.y * 64, b = blockIdx.z;
    int t = threadIdx.x;
    const float* xb = x + ((size_t)b * 512 + ct) * 1024 + nt;
#pragma unroll
    for (int p = 0; p < 4; ++p) {
        int c = p * 16 + (t >> 4), n4 = (t & 15) * 4;
        float4 v = *(const float4*)(xb + (size_t)c * 1024 + n4);
        xs[c][n4] = v.x; xs[c][n4 + 1] = v.y; xs[c][n4 + 2] = v.z; xs[c][n4 + 3] = v.w;
    }
    __syncthreads();
    int nl = t >> 2, part = t & 3;
    short* rowp = xT2 + ((size_t)b * 1024 + nt + nl) * 1536;
#pragma unroll
    for (int g = 0; g < 2; ++g) {
        short8 hi, lo;
#pragma unroll
        for (int j = 0; j < 8; ++j) {
            float f = xs[part * 16 + g * 8 + j][nl];
            short h = f2bf(f);
            hi[j] = h; lo[j] = f2bf(f - bf2f(h));
        }
        int c = ct + part * 16 + g * 8;
        *(short8*)(rowp + c)        = hi;
        *(short8*)(rowp + 512 + c)  = lo;
        *(short8*)(rowp + 1024 + c) = hi;
    }
}

// rel2[h][n][64] fp16
__global__ void k_prep_rel(const float* __restrict__ rel_h, const float* __restrict__ rel_w,
                           _Float16* __restrict__ rel2) {
    int tid = blockIdx.x * 256 + threadIdx.x;   // 65536
    int h = tid >> 13;
    int rem = tid & 8191;
    int n = rem >> 3;
    int g = rem & 7;
    int hh = n & 31, ww = n >> 5;
    half8 o;
#pragma unroll
    for (int j = 0; j < 8; ++j) {
        int d = g * 8 + j;
        o[j] = (_Float16)(rel_h[(h * 64 + d) * 32 + hh] + rel_w[(h * 64 + d) * 32 + ww]);
    }
    *(half8*)(rel2 + ((size_t)h * 1024 + n) * 64 + g * 8) = o;
}

// Split-bf16 GEMM, BK=64 (two R5-swizzled 32-K sub-tiles per LDS buffer).
// glds16 staging; fused epilogue writes q2/k2 ([bh][n][d]) and vb ([bh][d][n]).
__global__ __launch_bounds__(256, 3) void k_proj(const short* __restrict__ A2,
                                                 const short* __restrict__ xT2,
                                                 const float* __restrict__ bias2,
                                                 _Float16* __restrict__ q2,
                                                 _Float16* __restrict__ k2,
                                                 _Float16* __restrict__ vb) {
    __shared__ __align__(16) short As[8192];   // [2 kh][128 rows][32 shorts], swizzled
    __shared__ __align__(16) short Bs[8192];
    int t = threadIdx.x;
    int lane = t & 63, w = t >> 6;
    int lm = lane & 15, lq = lane >> 4;
    int wr = (w >> 1) * 64, wc = (w & 1) * 64;
    int mb = blockIdx.y * 128, nb = blockIdx.x * 128, b = blockIdx.z;
    int rl = lane >> 2;                                   // row within 16-row group
    int csw = ((lane & 3) ^ ((lane >> 3) & 3)) * 8;       // swizzled col (shorts)
    const short* Ag0 = A2 + (size_t)(mb + w * 32 + rl) * 1536 + csw;
    const short* Ag1 = Ag0 + 16 * 1536;
    const short* Bg0 = xT2 + ((size_t)b * 1024 + nb + w * 32 + rl) * 1536 + csw;
    const short* Bg1 = Bg0 + 16 * 1536;
    f32x4 acc[4][4];
#pragma unroll
    for (int i = 0; i < 4; ++i)
#pragma unroll
        for (int j = 0; j < 4; ++j) acc[i][j] = {0.f, 0.f, 0.f, 0.f};
    int fsw = (lq ^ ((lm >> 1) & 3)) * 8;                 // fragment-read swizzle
    for (int k0 = 0; k0 < 1536; k0 += 64) {
#pragma unroll
        for (int kh = 0; kh < 2; ++kh) {
            int ko = k0 + kh * 32;
            glds16(Ag0 + ko, &As[kh * 4096 + (w * 32) * 32]);
            glds16(Ag1 + ko, &As[kh * 4096 + (w * 32 + 16) * 32]);
            glds16(Bg0 + ko, &Bs[kh * 4096 + (w * 32) * 32]);
            glds16(Bg1 + ko, &Bs[kh * 4096 + (w * 32 + 16) * 32]);
        }
        __syncthreads();
#pragma unroll
        for (int kh = 0; kh < 2; ++kh) {
            short8 af[4], bfr[4];
#pragma unroll
            for (int mt = 0; mt < 4; ++mt)
                af[mt] = *(short8*)&As[kh * 4096 + (wr + mt * 16 + lm) * 32 + fsw];
#pragma unroll
            for (int nt = 0; nt < 4; ++nt)
                bfr[nt] = *(short8*)&Bs[kh * 4096 + (wc + nt * 16 + lm) * 32 + fsw];
#pragma unroll
            for (int mt = 0; mt < 4; ++mt)
#pragma unroll
                for (int nt = 0; nt < 4; ++nt)
                    acc[mt][nt] = __builtin_amdgcn_mfma_f32_16x16x32_bf16(af[mt], bfr[nt], acc[mt][nt], 0, 0, 0);
        }
        __syncthreads();
    }
    // Epilogue: section 0=q (rows 0-511), 1=k, 2=v; head-aligned since (mb+wr)%64==0
    int sect = mb >> 9;
    int hloc = ((mb & 511) + wr) >> 6;
    size_t bh = (size_t)b * 8 + hloc;
    if (sect < 2) {
        _Float16* dst = (sect == 0 ? q2 : k2) + bh * 1024 * 64;
#pragma unroll
        for (int mt = 0; mt < 4; ++mt) {
            int d0 = mt * 16 + lq * 4;
            float bi0 = bias2[mb + wr + d0];
            float bi1 = bias2[mb + wr + d0 + 1];
            float bi2 = bias2[mb + wr + d0 + 2];
            float bi3 = bias2[mb + wr + d0 + 3];
#pragma unroll
            for (int nt = 0; nt < 4; ++nt) {
                int n = nb + wc + nt * 16 + lm;
                half4 o;
                o[0] = (_Float16)(acc[mt][nt][0] + bi0);
                o[1] = (_Float16)(acc[mt][nt][1] + bi1);
                o[2] = (_Float16)(acc[mt][nt][2] + bi2);
                o[3] = (_Float16)(acc[mt][nt][3] + bi3);
                *(half4*)(dst + (size_t)n * 64 + d0) = o;
            }
        }
    } else {
        _Float16* dst = vb + bh * 64 * 1024;
#pragma unroll
        for (int mt = 0; mt < 4; ++mt)
#pragma unroll
            for (int reg = 0; reg < 4; ++reg) {
                int d = mt * 16 + lq * 4 + reg;
                float bi = bias2[mb + wr + d];
#pragma unroll
                for (int nt = 0; nt < 4; ++nt) {
                    int n = nb + wc + nt * 16 + lm;
                    dst[(size_t)d * 1024 + n] = (_Float16)(acc[mt][nt][reg] + bi);
                }
            }
    }
}

// Flash attention, fp16, S^T orientation. Prefetch pattern: ds_write(tile kt)
// -> barrier -> issue loads for tile kt+1 (named scalar uint4s, unconditional)
// -> compute -> barrier. Loads overlap the full compute phase; no arrays, no
// conditionals -> no scratch spill (R6 lesson: WRITE_SIZE 409 MB of spills).
__global__ __launch_bounds__(256, 4) void k_attn(const _Float16* __restrict__ q2,
                                                 const _Float16* __restrict__ k2,
                                                 const _Float16* __restrict__ rel2,
                                                 const _Float16* __restrict__ vb,
                                                 float* __restrict__ out) {
    __shared__ __align__(16) char pool[35840];
    _Float16* kb_s = (_Float16*)pool;            // [64][136] = 17408 B (phase-0: qa rows)
    _Float16* v_s  = (_Float16*)(pool + 17408);  // [64][72]  =  9216 B
    _Float16* p_s  = (_Float16*)(pool + 26624);  // [64 m][72 n] = 9216 B (wave-private rows)
    int t = threadIdx.x;
    int lane = t & 63, w = t >> 6;
    int lm = lane & 15, lq = lane >> 4;
    int mt0 = blockIdx.x, h = blockIdx.y, b = blockIdx.z;
    size_t bh = (size_t)b * 8 + h;
    const _Float16* q2b = q2 + bh * 1024 * 64;
    const _Float16* k2b = k2 + bh * 1024 * 64;
    const _Float16* relb = rel2 + (size_t)h * 1024 * 64;
    const _Float16* vbb = vb + bh * 64 * 1024;
    float* outb = out + bh * 64 * 1024 + mt0 * 64;

    int r = t >> 2, part = t & 3;
    const _Float16* ksrc = ((part < 2) ? (k2b + part * 32) : (q2b + (part - 2) * 32));
    int vc = (t & 3) * 16;
    const _Float16* vsrcb = vbb + (size_t)r * 1024 + vc;
    _Float16* kdst = kb_s + r * 136 + part * 32;
    _Float16* vdst = v_s + r * 72 + vc;

    // prefetch tile 0 into named scalar registers
    uint4 kc0, kc1, kc2, kc3, vv0, vv1;
    {
        const uint4* s_ = (const uint4*)(ksrc + (size_t)r * 64);
        kc0 = s_[0]; kc1 = s_[1]; kc2 = s_[2]; kc3 = s_[3];
        const uint4* v_ = (const uint4*)vsrcb;
        vv0 = v_[0]; vv1 = v_[1];
    }

    // Phase 0: stage A-side rows [q | rel] for m = mt0*64 .. +63 (aliases kb_s)
    {
        int n = mt0 * 64 + r;
        const _Float16* src = (part < 2) ? (q2b + (size_t)n * 64 + part * 32)
                                         : (relb + (size_t)n * 64 + (part - 2) * 32);
        ((uint4*)kdst)[0] = ((const uint4*)src)[0];
        ((uint4*)kdst)[1] = ((const uint4*)src)[1];
        ((uint4*)kdst)[2] = ((const uint4*)src)[2];
        ((uint4*)kdst)[3] = ((const uint4*)src)[3];
    }
    __syncthreads();
    // q fragment as MFMA *B* operand: col=lm -> m = w*16+lm, k = kk*32 + lq*8 + j
    half8 ah[4];
#pragma unroll
    for (int kk = 0; kk < 4; ++kk)
        ah[kk] = *(half8*)&kb_s[(w * 16 + lm) * 136 + kk * 32 + lq * 8];
    f32x4 acco[4];
#pragma unroll
    for (int i = 0; i < 4; ++i) acco[i] = {0.f, 0.f, 0.f, 0.f};
    float mrun = -3e38f, lrun = 0.f;

    for (int kt = 0; kt < 16; ++kt) {
        // write staged tile kt (own-wave rows; in-order per-wave LDS vs ah reads;
        // cross-wave safety from the previous iteration's trailing barrier)
        ((uint4*)kdst)[0] = kc0;
        ((uint4*)kdst)[1] = kc1;
        ((uint4*)kdst)[2] = kc2;
        ((uint4*)kdst)[3] = kc3;
        ((uint4*)vdst)[0] = vv0;
        ((uint4*)vdst)[1] = vv1;
        __syncthreads();
        // issue tile kt+1 loads (modulo wrap keeps them unconditional; last
        // iteration re-reads tile 0 from L2, harmless)
        int nn = ((kt + 1) & 15) * 64;
        const uint4* s_ = (const uint4*)(ksrc + (size_t)(nn + r) * 64);
        uint4 kn0 = s_[0], kn1 = s_[1], kn2 = s_[2], kn3 = s_[3];
        const uint4* v_ = (const uint4*)(vsrcb + nn);
        uint4 vn0 = v_[0], vn1 = v_[1];
        // S^T[n][m]: sac[ct][reg] -> n = ct*16 + lq*4 + reg, m = w*16 + lm
        f32x4 sac[4];
#pragma unroll
        for (int ct = 0; ct < 4; ++ct) sac[ct] = {0.f, 0.f, 0.f, 0.f};
#pragma unroll
        for (int ct = 0; ct < 4; ++ct) {
            half8 kf[4];
#pragma unroll
            for (int kk = 0; kk < 4; ++kk)
                kf[kk] = *(half8*)&kb_s[(ct * 16 + lm) * 136 + kk * 32 + lq * 8];
#pragma unroll
            for (int kk = 0; kk < 4; ++kk)
                sac[ct] = __builtin_amdgcn_mfma_f32_16x16x32_f16(kf[kk], ah[kk], sac[ct], 0, 0, 0);
        }
        // online softmax over n for column m (per-lane; lq-replicated via 2 shuffles)
        float mx = -3e38f;
#pragma unroll
        for (int ct = 0; ct < 4; ++ct)
#pragma unroll
            for (int reg = 0; reg < 4; ++reg) mx = fmaxf(mx, sac[ct][reg]);
        mx = fmaxf(mx, __shfl_xor(mx, 16));
        mx = fmaxf(mx, __shfl_xor(mx, 32));
        float mnew = fmaxf(mrun, mx);
        float al_ = __expf(mrun - mnew);
        float ps[4][4];
        float rs = 0.f;
#pragma unroll
        for (int ct = 0; ct < 4; ++ct)
#pragma unroll
            for (int reg = 0; reg < 4; ++reg) {
                float p = __expf(sac[ct][reg] - mnew);
                ps[ct][reg] = p;
                rs += p;
            }
        rs += __shfl_xor(rs, 16);
        rs += __shfl_xor(rs, 32);
        lrun = lrun * al_ + rs;
        mrun = mnew;
#pragma unroll
        for (int dt = 0; dt < 4; ++dt) {
            acco[dt][0] *= al_; acco[dt][1] *= al_;
            acco[dt][2] *= al_; acco[dt][3] *= al_;
        }
        // store P rows [m][n] (wave-private rows m = w*16 + 0..15): b64 per ct
#pragma unroll
        for (int ct = 0; ct < 4; ++ct) {
            half4 o;
            o[0] = (_Float16)ps[ct][0]; o[1] = (_Float16)ps[ct][1];
            o[2] = (_Float16)ps[ct][2]; o[3] = (_Float16)ps[ct][3];
            *(half4*)&p_s[(w * 16 + lm) * 72 + ct * 16 + lq * 4] = o;
        }
        // PV: out^T[d][m] += v[d][n] * P^T[n][m]
        half8 pfr[2];
#pragma unroll
        for (int ch = 0; ch < 2; ++ch)
            pfr[ch] = *(half8*)&p_s[(w * 16 + lm) * 72 + ch * 32 + lq * 8];
#pragma unroll
        for (int dt = 0; dt < 4; ++dt) {
            half8 vf0 = *(half8*)&v_s[(dt * 16 + lm) * 72 + lq * 8];
            half8 vf1 = *(half8*)&v_s[(dt * 16 + lm) * 72 + 32 + lq * 8];
            acco[dt] = __builtin_amdgcn_mfma_f32_16x16x32_f16(vf0, pfr[0], acco[dt], 0, 0, 0);
            acco[dt] = __builtin_amdgcn_mfma_f32_16x16x32_f16(vf1, pfr[1], acco[dt], 0, 0, 0);
        }
        __syncthreads();   // all reads of kb_s/v_s done before next ds_write
        kc0 = kn0; kc1 = kn1; kc2 = kn2; kc3 = kn3;
        vv0 = vn0; vv1 = vn1;
    }
    float li = 1.f / lrun;
#pragma unroll
    for (int dt = 0; dt < 4; ++dt)
#pragma unroll
        for (int reg = 0; reg < 4; ++reg) {
            int d = dt * 16 + lq * 4 + reg;
            outb[(size_t)d * 1024 + w * 16 + lm] = acco[dt][reg] * li;
        }
}

extern "C" void kernel_launch(void* const* d_in, const int* in_sizes, int n_in,
                              void* d_out, int out_size, void* d_ws, size_t ws_size,
                              hipStream_t stream) {
    const float* x     = (const float*)d_in[0];
    const float* Wq    = (const float*)d_in[1];
    const float* bq    = (const float*)d_in[2];
    const float* Wk    = (const float*)d_in[3];
    const float* bk    = (const float*)d_in[4];
    const float* Wv    = (const float*)d_in[5];
    const float* bv    = (const float*)d_in[6];
    const float* rel_h = (const float*)d_in[7];
    const float* rel_w = (const float*)d_in[8];
    char* ws = (char*)d_ws;
    short* A2      = (short*)(ws);                  //  4,718,592 B
    float* bias2   = (float*)(ws + 4718592);        //      6,144 B -> 4,724,736
    short* xT2     = (short*)(ws + 4724736);        // 25,165,824 B -> 29,890,560
    _Float16* q2   = (_Float16*)(ws + 29890560);    //  8,388,608 B -> 38,279,168
    _Float16* k2   = (_Float16*)(ws + 38279168);    //  8,388,608 B -> 46,667,776
    _Float16* vb   = (_Float16*)(ws + 46667776);    //  8,388,608 B -> 55,056,384
    _Float16* rel2 = (_Float16*)(ws + 55056384);    //  1,048,576 B -> 56,104,960
    float* out = (float*)d_out;

    hipLaunchKernelGGL(k_pack_w,   dim3(384),      dim3(256), 0, stream, Wq, Wk, Wv, bq, bk, bv, A2, bias2);
    hipLaunchKernelGGL(k_prep_x,   dim3(16, 8, 8), dim3(256), 0, stream, x, xT2);
    hipLaunchKernelGGL(k_prep_rel, dim3(256),      dim3(256), 0, stream, rel_h, rel_w, rel2);
    hipLaunchKernelGGL(k_proj,     dim3(8, 12, 8), dim3(256), 0, stream, A2, xT2, bias2, q2, k2, vb);
    hipLaunchKernelGGL(k_attn,     dim3(16, 8, 8), dim3(256), 0, stream, q2, k2, rel2, vb, out);
}

// Round 8
// 161.151 us; speedup vs baseline: 1.7313x; 1.1889x over previous
//
#include <hip/hip_runtime.h>

typedef short short8 __attribute__((ext_vector_type(8)));
typedef _Float16 half8 __attribute__((ext_vector_type(8)));
typedef _Float16 half4 __attribute__((ext_vector_type(4)));
typedef float f32x4 __attribute__((ext_vector_type(4)));

__device__ __forceinline__ void glds16(const void* g, void* l) {
    __builtin_amdgcn_global_load_lds(
        (const __attribute__((address_space(1))) unsigned int*)g,
        (__attribute__((address_space(3))) unsigned int*)l, 16, 0, 0);
}

// ---------------------------------------------------------------------------
// Sizes: B=8, C=512, H=8, D=64, N=1024. Projection: M=1536 (q|k|v), K=512 fp16.
// ---------------------------------------------------------------------------

// Pack Wq/Wk/Wv -> Wf[1536][512] fp16, bias2[1536] fp32.
__global__ void k_pack_w(const float* __restrict__ Wq, const float* __restrict__ Wk,
                         const float* __restrict__ Wv, const float* __restrict__ bq,
                         const float* __restrict__ bk, const float* __restrict__ bv,
                         _Float16* __restrict__ Wf, float* __restrict__ bias2) {
    int t = blockIdx.x * 256 + threadIdx.x;      // 98304 threads
    int m = t >> 6;
    int c8 = (t & 63) << 3;
    const float* src = (m < 512) ? (Wq + m * 512)
                     : (m < 1024 ? (Wk + (m - 512) * 512) : (Wv + (m - 1024) * 512));
    float4 v0 = *(const float4*)(src + c8);
    float4 v1 = *(const float4*)(src + c8 + 4);
    half8 o;
    o[0] = (_Float16)v0.x; o[1] = (_Float16)v0.y; o[2] = (_Float16)v0.z; o[3] = (_Float16)v0.w;
    o[4] = (_Float16)v1.x; o[5] = (_Float16)v1.y; o[6] = (_Float16)v1.z; o[7] = (_Float16)v1.w;
    *(half8*)(Wf + (size_t)m * 512 + c8) = o;
    if (t < 1536)
        bias2[t] = (t < 512) ? bq[t] : (t < 1024 ? bk[t - 512] : bv[t - 1024]);
}

// Transpose x[b][c][n] -> xTf[b][n][512] fp16 (k-contiguous rows)
__global__ void k_prep_x(const float* __restrict__ x, _Float16* __restrict__ xTf) {
    __shared__ float xs[64][65];
    int nt = blockIdx.x * 64, ct = blockIdx.y * 64, b = blockIdx.z;
    int t = threadIdx.x;
    const float* xb = x + ((size_t)b * 512 + ct) * 1024 + nt;
#pragma unroll
    for (int p = 0; p < 4; ++p) {
        int c = p * 16 + (t >> 4), n4 = (t & 15) * 4;
        float4 v = *(const float4*)(xb + (size_t)c * 1024 + n4);
        xs[c][n4] = v.x; xs[c][n4 + 1] = v.y; xs[c][n4 + 2] = v.z; xs[c][n4 + 3] = v.w;
    }
    __syncthreads();
    int nl = t >> 2, part = t & 3;
    _Float16* rowp = xTf + ((size_t)b * 1024 + nt + nl) * 512;
#pragma unroll
    for (int g = 0; g < 2; ++g) {
        half8 o;
#pragma unroll
        for (int j = 0; j < 8; ++j)
            o[j] = (_Float16)xs[part * 16 + g * 8 + j][nl];
        *(half8*)(rowp + ct + part * 16 + g * 8) = o;
    }
}

// rel2[h][n][64] fp16
__global__ void k_prep_rel(const float* __restrict__ rel_h, const float* __restrict__ rel_w,
                           _Float16* __restrict__ rel2) {
    int tid = blockIdx.x * 256 + threadIdx.x;   // 65536
    int h = tid >> 13;
    int rem = tid & 8191;
    int n = rem >> 3;
    int g = rem & 7;
    int hh = n & 31, ww = n >> 5;
    half8 o;
#pragma unroll
    for (int j = 0; j < 8; ++j) {
        int d = g * 8 + j;
        o[j] = (_Float16)(rel_h[(h * 64 + d) * 32 + hh] + rel_w[(h * 64 + d) * 32 + ww]);
    }
    *(half8*)(rel2 + ((size_t)h * 1024 + n) * 64 + g * 8) = o;
}

// fp16 GEMM K=512, BK=64 (two swizzled 32-K sub-tiles per LDS buffer).
// glds16 staging; fused epilogue writes q2/k2 ([bh][n][d]) and vb ([bh][d][n]).
__global__ __launch_bounds__(256, 3) void k_proj(const _Float16* __restrict__ Wf,
                                                 const _Float16* __restrict__ xTf,
                                                 const float* __restrict__ bias2,
                                                 _Float16* __restrict__ q2,
                                                 _Float16* __restrict__ k2,
                                                 _Float16* __restrict__ vb) {
    __shared__ __align__(16) _Float16 As[8192];   // [2 kh][128 rows][32 halfs], swizzled
    __shared__ __align__(16) _Float16 Bs[8192];
    int t = threadIdx.x;
    int lane = t & 63, w = t >> 6;
    int lm = lane & 15, lq = lane >> 4;
    int wr = (w >> 1) * 64, wc = (w & 1) * 64;
    int mb = blockIdx.y * 128, nb = blockIdx.x * 128, b = blockIdx.z;
    int rl = lane >> 2;                                   // row within 16-row group
    int csw = ((lane & 3) ^ ((lane >> 3) & 3)) * 8;       // swizzled col (halfs)
    const _Float16* Ag0 = Wf + (size_t)(mb + w * 32 + rl) * 512 + csw;
    const _Float16* Ag1 = Ag0 + 16 * 512;
    const _Float16* Bg0 = xTf + ((size_t)b * 1024 + nb + w * 32 + rl) * 512 + csw;
    const _Float16* Bg1 = Bg0 + 16 * 512;
    f32x4 acc[4][4];
#pragma unroll
    for (int i = 0; i < 4; ++i)
#pragma unroll
        for (int j = 0; j < 4; ++j) acc[i][j] = {0.f, 0.f, 0.f, 0.f};
    int fsw = (lq ^ ((lm >> 1) & 3)) * 8;                 // fragment-read swizzle
    for (int k0 = 0; k0 < 512; k0 += 64) {
#pragma unroll
        for (int kh = 0; kh < 2; ++kh) {
            int ko = k0 + kh * 32;
            glds16(Ag0 + ko, &As[kh * 4096 + (w * 32) * 32]);
            glds16(Ag1 + ko, &As[kh * 4096 + (w * 32 + 16) * 32]);
            glds16(Bg0 + ko, &Bs[kh * 4096 + (w * 32) * 32]);
            glds16(Bg1 + ko, &Bs[kh * 4096 + (w * 32 + 16) * 32]);
        }
        __syncthreads();
#pragma unroll
        for (int kh = 0; kh < 2; ++kh) {
            half8 af[4], bfr[4];
#pragma unroll
            for (int mt = 0; mt < 4; ++mt)
                af[mt] = *(half8*)&As[kh * 4096 + (wr + mt * 16 + lm) * 32 + fsw];
#pragma unroll
            for (int nt = 0; nt < 4; ++nt)
                bfr[nt] = *(half8*)&Bs[kh * 4096 + (wc + nt * 16 + lm) * 32 + fsw];
#pragma unroll
            for (int mt = 0; mt < 4; ++mt)
#pragma unroll
                for (int nt = 0; nt < 4; ++nt)
                    acc[mt][nt] = __builtin_amdgcn_mfma_f32_16x16x32_f16(af[mt], bfr[nt], acc[mt][nt], 0, 0, 0);
        }
        __syncthreads();
    }
    // Epilogue: section 0=q (rows 0-511), 1=k, 2=v; head-aligned since (mb+wr)%64==0
    int sect = mb >> 9;
    int hloc = ((mb & 511) + wr) >> 6;
    size_t bh = (size_t)b * 8 + hloc;
    if (sect < 2) {
        _Float16* dst = (sect == 0 ? q2 : k2) + bh * 1024 * 64;
#pragma unroll
        for (int mt = 0; mt < 4; ++mt) {
            int d0 = mt * 16 + lq * 4;
            float bi0 = bias2[mb + wr + d0];
            float bi1 = bias2[mb + wr + d0 + 1];
            float bi2 = bias2[mb + wr + d0 + 2];
            float bi3 = bias2[mb + wr + d0 + 3];
#pragma unroll
            for (int nt = 0; nt < 4; ++nt) {
                int n = nb + wc + nt * 16 + lm;
                half4 o;
                o[0] = (_Float16)(acc[mt][nt][0] + bi0);
                o[1] = (_Float16)(acc[mt][nt][1] + bi1);
                o[2] = (_Float16)(acc[mt][nt][2] + bi2);
                o[3] = (_Float16)(acc[mt][nt][3] + bi3);
                *(half4*)(dst + (size_t)n * 64 + d0) = o;
            }
        }
    } else {
        _Float16* dst = vb + bh * 64 * 1024;
#pragma unroll
        for (int mt = 0; mt < 4; ++mt)
#pragma unroll
            for (int reg = 0; reg < 4; ++reg) {
                int d = mt * 16 + lq * 4 + reg;
                float bi = bias2[mb + wr + d];
#pragma unroll
                for (int nt = 0; nt < 4; ++nt) {
                    int n = nb + wc + nt * 16 + lm;
                    dst[(size_t)d * 1024 + n] = (_Float16)(acc[mt][nt][reg] + bi);
                }
            }
    }
}

// Flash attention, fp16, S^T orientation, R7 prefetch pattern.
// 1D grid with XCD-locality decode: lin & 63 = (b,h) so all 16 query-tiles of
// one (b,h) share an XCD (round-robin dispatch) -> K/V stream hits L2.
__global__ __launch_bounds__(256, 4) void k_attn(const _Float16* __restrict__ q2,
                                                 const _Float16* __restrict__ k2,
                                                 const _Float16* __restrict__ rel2,
                                                 const _Float16* __restrict__ vb,
                                                 float* __restrict__ out) {
    __shared__ __align__(16) char pool[35840];
    _Float16* kb_s = (_Float16*)pool;            // [64][136] = 17408 B (phase-0: qa rows)
    _Float16* v_s  = (_Float16*)(pool + 17408);  // [64][72]  =  9216 B
    _Float16* p_s  = (_Float16*)(pool + 26624);  // [64 m][72 n] = 9216 B (wave-private rows)
    int t = threadIdx.x;
    int lane = t & 63, w = t >> 6;
    int lm = lane & 15, lq = lane >> 4;
    int lin = blockIdx.x;
    int mt0 = lin >> 6;
    int bh_ = lin & 63;
    int h = bh_ & 7, b = bh_ >> 3;
    size_t bh = (size_t)b * 8 + h;
    const _Float16* q2b = q2 + bh * 1024 * 64;
    const _Float16* k2b = k2 + bh * 1024 * 64;
    const _Float16* relb = rel2 + (size_t)h * 1024 * 64;
    const _Float16* vbb = vb + bh * 64 * 1024;
    float* outb = out + bh * 64 * 1024 + mt0 * 64;

    int r = t >> 2, part = t & 3;
    const _Float16* ksrc = ((part < 2) ? (k2b + part * 32) : (q2b + (part - 2) * 32));
    int vc = (t & 3) * 16;
    const _Float16* vsrcb = vbb + (size_t)r * 1024 + vc;
    _Float16* kdst = kb_s + r * 136 + part * 32;
    _Float16* vdst = v_s + r * 72 + vc;

    // prefetch tile 0 into named scalar registers
    uint4 kc0, kc1, kc2, kc3, vv0, vv1;
    {
        const uint4* s_ = (const uint4*)(ksrc + (size_t)r * 64);
        kc0 = s_[0]; kc1 = s_[1]; kc2 = s_[2]; kc3 = s_[3];
        const uint4* v_ = (const uint4*)vsrcb;
        vv0 = v_[0]; vv1 = v_[1];
    }

    // Phase 0: stage A-side rows [q | rel] for m = mt0*64 .. +63 (aliases kb_s)
    {
        int n = mt0 * 64 + r;
        const _Float16* src = (part < 2) ? (q2b + (size_t)n * 64 + part * 32)
                                         : (relb + (size_t)n * 64 + (part - 2) * 32);
        ((uint4*)kdst)[0] = ((const uint4*)src)[0];
        ((uint4*)kdst)[1] = ((const uint4*)src)[1];
        ((uint4*)kdst)[2] = ((const uint4*)src)[2];
        ((uint4*)kdst)[3] = ((const uint4*)src)[3];
    }
    __syncthreads();
    // q fragment as MFMA *B* operand: col=lm -> m = w*16+lm, k = kk*32 + lq*8 + j
    half8 ah[4];
#pragma unroll
    for (int kk = 0; kk < 4; ++kk)
        ah[kk] = *(half8*)&kb_s[(w * 16 + lm) * 136 + kk * 32 + lq * 8];
    f32x4 acco[4];
#pragma unroll
    for (int i = 0; i < 4; ++i) acco[i] = {0.f, 0.f, 0.f, 0.f};
    float mrun = -3e38f, lrun = 0.f;

    for (int kt = 0; kt < 16; ++kt) {
        // write staged tile kt (own-wave rows; cross-wave safety from the
        // previous iteration's trailing barrier)
        ((uint4*)kdst)[0] = kc0;
        ((uint4*)kdst)[1] = kc1;
        ((uint4*)kdst)[2] = kc2;
        ((uint4*)kdst)[3] = kc3;
        ((uint4*)vdst)[0] = vv0;
        ((uint4*)vdst)[1] = vv1;
        __syncthreads();
        // issue tile kt+1 loads (modulo wrap keeps them unconditional)
        int nn = ((kt + 1) & 15) * 64;
        const uint4* s_ = (const uint4*)(ksrc + (size_t)(nn + r) * 64);
        uint4 kn0 = s_[0], kn1 = s_[1], kn2 = s_[2], kn3 = s_[3];
        const uint4* v_ = (const uint4*)(vsrcb + nn);
        uint4 vn0 = v_[0], vn1 = v_[1];
        // S^T[n][m]: sac[ct][reg] -> n = ct*16 + lq*4 + reg, m = w*16 + lm
        f32x4 sac[4];
#pragma unroll
        for (int ct = 0; ct < 4; ++ct) sac[ct] = {0.f, 0.f, 0.f, 0.f};
#pragma unroll
        for (int ct = 0; ct < 4; ++ct) {
            half8 kf[4];
#pragma unroll
            for (int kk = 0; kk < 4; ++kk)
                kf[kk] = *(half8*)&kb_s[(ct * 16 + lm) * 136 + kk * 32 + lq * 8];
#pragma unroll
            for (int kk = 0; kk < 4; ++kk)
                sac[ct] = __builtin_amdgcn_mfma_f32_16x16x32_f16(kf[kk], ah[kk], sac[ct], 0, 0, 0);
        }
        // online softmax over n for column m (per-lane; lq-replicated via 2 shuffles)
        float mx = -3e38f;
#pragma unroll
        for (int ct = 0; ct < 4; ++ct)
#pragma unroll
            for (int reg = 0; reg < 4; ++reg) mx = fmaxf(mx, sac[ct][reg]);
        mx = fmaxf(mx, __shfl_xor(mx, 16));
        mx = fmaxf(mx, __shfl_xor(mx, 32));
        float mnew = fmaxf(mrun, mx);
        float al_ = __expf(mrun - mnew);
        float ps[4][4];
        float rs = 0.f;
#pragma unroll
        for (int ct = 0; ct < 4; ++ct)
#pragma unroll
            for (int reg = 0; reg < 4; ++reg) {
                float p = __expf(sac[ct][reg] - mnew);
                ps[ct][reg] = p;
                rs += p;
            }
        rs += __shfl_xor(rs, 16);
        rs += __shfl_xor(rs, 32);
        lrun = lrun * al_ + rs;
        mrun = mnew;
#pragma unroll
        for (int dt = 0; dt < 4; ++dt) {
            acco[dt][0] *= al_; acco[dt][1] *= al_;
            acco[dt][2] *= al_; acco[dt][3] *= al_;
        }
        // store P rows [m][n] (wave-private rows m = w*16 + 0..15): b64 per ct
#pragma unroll
        for (int ct = 0; ct < 4; ++ct) {
            half4 o;
            o[0] = (_Float16)ps[ct][0]; o[1] = (_Float16)ps[ct][1];
            o[2] = (_Float16)ps[ct][2]; o[3] = (_Float16)ps[ct][3];
            *(half4*)&p_s[(w * 16 + lm) * 72 + ct * 16 + lq * 4] = o;
        }
        // PV: out^T[d][m] += v[d][n] * P^T[n][m]
        half8 pfr[2];
#pragma unroll
        for (int ch = 0; ch < 2; ++ch)
            pfr[ch] = *(half8*)&p_s[(w * 16 + lm) * 72 + ch * 32 + lq * 8];
#pragma unroll
        for (int dt = 0; dt < 4; ++dt) {
            half8 vf0 = *(half8*)&v_s[(dt * 16 + lm) * 72 + lq * 8];
            half8 vf1 = *(half8*)&v_s[(dt * 16 + lm) * 72 + 32 + lq * 8];
            acco[dt] = __builtin_amdgcn_mfma_f32_16x16x32_f16(vf0, pfr[0], acco[dt], 0, 0, 0);
            acco[dt] = __builtin_amdgcn_mfma_f32_16x16x32_f16(vf1, pfr[1], acco[dt], 0, 0, 0);
        }
        __syncthreads();   // all reads of kb_s/v_s done before next ds_write
        kc0 = kn0; kc1 = kn1; kc2 = kn2; kc3 = kn3;
        vv0 = vn0; vv1 = vn1;
    }
    float li = 1.f / lrun;
#pragma unroll
    for (int dt = 0; dt < 4; ++dt)
#pragma unroll
        for (int reg = 0; reg < 4; ++reg) {
            int d = dt * 16 + lq * 4 + reg;
            outb[(size_t)d * 1024 + w * 16 + lm] = acco[dt][reg] * li;
        }
}

extern "C" void kernel_launch(void* const* d_in, const int* in_sizes, int n_in,
                              void* d_out, int out_size, void* d_ws, size_t ws_size,
                              hipStream_t stream) {
    const float* x     = (const float*)d_in[0];
    const float* Wq    = (const float*)d_in[1];
    const float* bq    = (const float*)d_in[2];
    const float* Wk    = (const float*)d_in[3];
    const float* bk    = (const float*)d_in[4];
    const float* Wv    = (const float*)d_in[5];
    const float* bv    = (const float*)d_in[6];
    const float* rel_h = (const float*)d_in[7];
    const float* rel_w = (const float*)d_in[8];
    char* ws = (char*)d_ws;
    _Float16* Wf   = (_Float16*)(ws);               //  1,572,864 B
    float* bias2   = (float*)(ws + 1572864);        //      6,144 B -> 1,579,008
    _Float16* xTf  = (_Float16*)(ws + 1579008);     //  8,388,608 B -> 9,967,616
    _Float16* q2   = (_Float16*)(ws + 9967616);     //  8,388,608 B -> 18,356,224
    _Float16* k2   = (_Float16*)(ws + 18356224);    //  8,388,608 B -> 26,744,832
    _Float16* vb   = (_Float16*)(ws + 26744832);    //  8,388,608 B -> 35,133,440
    _Float16* rel2 = (_Float16*)(ws + 35133440);    //  1,048,576 B -> 36,182,016
    float* out = (float*)d_out;

    hipLaunchKernelGGL(k_pack_w,   dim3(384),      dim3(256), 0, stream, Wq, Wk, Wv, bq, bk, bv, Wf, bias2);
    hipLaunchKernelGGL(k_prep_x,   dim3(16, 8, 8), dim3(256), 0, stream, x, xTf);
    hipLaunchKernelGGL(k_prep_rel, dim3(256),      dim3(256), 0, stream, rel_h, rel_w, rel2);
    hipLaunchKernelGGL(k_proj,     dim3(8, 12, 8), dim3(256), 0, stream, Wf, xTf, bias2, q2, k2, vb);
    hipLaunchKernelGGL(k_attn,     dim3(1024),     dim3(256), 0, stream, q2, k2, rel2, vb, out);
}

// Round 9
// 152.960 us; speedup vs baseline: 1.8240x; 1.0535x over previous
//
#include <hip/hip_runtime.h>

typedef _Float16 half8 __attribute__((ext_vector_type(8)));
typedef _Float16 half4 __attribute__((ext_vector_type(4)));
typedef float f32x4 __attribute__((ext_vector_type(4)));

__device__ __forceinline__ void glds16(const void* g, void* l) {
    __builtin_amdgcn_global_load_lds(
        (const __attribute__((address_space(1))) unsigned int*)g,
        (__attribute__((address_space(3))) unsigned int*)l, 16, 0, 0);
}

// ---------------------------------------------------------------------------
// Sizes: B=8, C=512, H=8, D=64, N=1024. Projection: M=1536 (q|k|v), K=512 fp16.
// ---------------------------------------------------------------------------

// Merged prep: [0,384) pack W->fp16; [384,1408) transpose x->fp16; [1408,1664) rel.
__global__ void k_prep_all(const float* __restrict__ Wq, const float* __restrict__ Wk,
                           const float* __restrict__ Wv, const float* __restrict__ bq,
                           const float* __restrict__ bk, const float* __restrict__ bv,
                           const float* __restrict__ x, const float* __restrict__ rel_h,
                           const float* __restrict__ rel_w, _Float16* __restrict__ Wf,
                           float* __restrict__ bias2, _Float16* __restrict__ xTf,
                           _Float16* __restrict__ rel2) {
    __shared__ float xs[64][65];
    int bid = blockIdx.x;
    if (bid < 384) {
        int t = bid * 256 + threadIdx.x;          // 98304 threads
        int m = t >> 6;
        int c8 = (t & 63) << 3;
        const float* src = (m < 512) ? (Wq + m * 512)
                         : (m < 1024 ? (Wk + (m - 512) * 512) : (Wv + (m - 1024) * 512));
        float4 v0 = *(const float4*)(src + c8);
        float4 v1 = *(const float4*)(src + c8 + 4);
        half8 o;
        o[0] = (_Float16)v0.x; o[1] = (_Float16)v0.y; o[2] = (_Float16)v0.z; o[3] = (_Float16)v0.w;
        o[4] = (_Float16)v1.x; o[5] = (_Float16)v1.y; o[6] = (_Float16)v1.z; o[7] = (_Float16)v1.w;
        *(half8*)(Wf + (size_t)m * 512 + c8) = o;
        if (t < 1536)
            bias2[t] = (t < 512) ? bq[t] : (t < 1024 ? bk[t - 512] : bv[t - 1024]);
    } else if (bid < 1408) {
        int i = bid - 384;
        int nt = (i & 15) << 6, ct = ((i >> 4) & 7) << 6, b = i >> 7;
        int t = threadIdx.x;
        const float* xb = x + ((size_t)b * 512 + ct) * 1024 + nt;
#pragma unroll
        for (int p = 0; p < 4; ++p) {
            int c = p * 16 + (t >> 4), n4 = (t & 15) * 4;
            float4 v = *(const float4*)(xb + (size_t)c * 1024 + n4);
            xs[c][n4] = v.x; xs[c][n4 + 1] = v.y; xs[c][n4 + 2] = v.z; xs[c][n4 + 3] = v.w;
        }
        __syncthreads();
        int nl = t >> 2, part = t & 3;
        _Float16* rowp = xTf + ((size_t)b * 1024 + nt + nl) * 512;
#pragma unroll
        for (int g = 0; g < 2; ++g) {
            half8 o;
#pragma unroll
            for (int j = 0; j < 8; ++j)
                o[j] = (_Float16)xs[part * 16 + g * 8 + j][nl];
            *(half8*)(rowp + ct + part * 16 + g * 8) = o;
        }
    } else {
        int tid = (bid - 1408) * 256 + threadIdx.x;   // 65536
        int h = tid >> 13;
        int rem = tid & 8191;
        int n = rem >> 3;
        int g = rem & 7;
        int hh = n & 31, ww = n >> 5;
        half8 o;
#pragma unroll
        for (int j = 0; j < 8; ++j) {
            int d = g * 8 + j;
            o[j] = (_Float16)(rel_h[(h * 64 + d) * 32 + hh] + rel_w[(h * 64 + d) * 32 + ww]);
        }
        *(half8*)(rel2 + ((size_t)h * 1024 + n) * 64 + g * 8) = o;
    }
}

// fp16 GEMM K=512, BK=64; glds16 + XOR-swizzled LDS. Epilogue writes q2 (scaled
// by log2e for the exp2 softmax), k2 ([bh][n][d]) and vb ([bh][d][n]).
__global__ __launch_bounds__(256, 3) void k_proj(const _Float16* __restrict__ Wf,
                                                 const _Float16* __restrict__ xTf,
                                                 const float* __restrict__ bias2,
                                                 _Float16* __restrict__ q2,
                                                 _Float16* __restrict__ k2,
                                                 _Float16* __restrict__ vb) {
    __shared__ __align__(16) _Float16 As[8192];   // [2 kh][128 rows][32 halfs], swizzled
    __shared__ __align__(16) _Float16 Bs[8192];
    int t = threadIdx.x;
    int lane = t & 63, w = t >> 6;
    int lm = lane & 15, lq = lane >> 4;
    int wr = (w >> 1) * 64, wc = (w & 1) * 64;
    int mb = blockIdx.y * 128, nb = blockIdx.x * 128, b = blockIdx.z;
    int rl = lane >> 2;                                   // row within 16-row group
    int csw = ((lane & 3) ^ ((lane >> 3) & 3)) * 8;       // swizzled col (halfs)
    const _Float16* Ag0 = Wf + (size_t)(mb + w * 32 + rl) * 512 + csw;
    const _Float16* Ag1 = Ag0 + 16 * 512;
    const _Float16* Bg0 = xTf + ((size_t)b * 1024 + nb + w * 32 + rl) * 512 + csw;
    const _Float16* Bg1 = Bg0 + 16 * 512;
    f32x4 acc[4][4];
#pragma unroll
    for (int i = 0; i < 4; ++i)
#pragma unroll
        for (int j = 0; j < 4; ++j) acc[i][j] = {0.f, 0.f, 0.f, 0.f};
    int fsw = (lq ^ ((lm >> 1) & 3)) * 8;                 // fragment-read swizzle
    for (int k0 = 0; k0 < 512; k0 += 64) {
#pragma unroll
        for (int kh = 0; kh < 2; ++kh) {
            int ko = k0 + kh * 32;
            glds16(Ag0 + ko, &As[kh * 4096 + (w * 32) * 32]);
            glds16(Ag1 + ko, &As[kh * 4096 + (w * 32 + 16) * 32]);
            glds16(Bg0 + ko, &Bs[kh * 4096 + (w * 32) * 32]);
            glds16(Bg1 + ko, &Bs[kh * 4096 + (w * 32 + 16) * 32]);
        }
        __syncthreads();
#pragma unroll
        for (int kh = 0; kh < 2; ++kh) {
            half8 af[4], bfr[4];
#pragma unroll
            for (int mt = 0; mt < 4; ++mt)
                af[mt] = *(half8*)&As[kh * 4096 + (wr + mt * 16 + lm) * 32 + fsw];
#pragma unroll
            for (int nt = 0; nt < 4; ++nt)
                bfr[nt] = *(half8*)&Bs[kh * 4096 + (wc + nt * 16 + lm) * 32 + fsw];
#pragma unroll
            for (int mt = 0; mt < 4; ++mt)
#pragma unroll
                for (int nt = 0; nt < 4; ++nt)
                    acc[mt][nt] = __builtin_amdgcn_mfma_f32_16x16x32_f16(af[mt], bfr[nt], acc[mt][nt], 0, 0, 0);
        }
        __syncthreads();
    }
    // Epilogue: section 0=q, 1=k, 2=v; head-aligned since (mb+wr)%64==0.
    // q scaled by log2e so k_attn can use native exp2 (S gets the factor exactly:
    // q is the A-half of q·k and the B-half of rel·q).
    int sect = mb >> 9;
    int hloc = ((mb & 511) + wr) >> 6;
    size_t bh = (size_t)b * 8 + hloc;
    if (sect < 2) {
        float sc = (sect == 0) ? 1.44269504089f : 1.0f;
        _Float16* dst = (sect == 0 ? q2 : k2) + bh * 1024 * 64;
#pragma unroll
        for (int mt = 0; mt < 4; ++mt) {
            int d0 = mt * 16 + lq * 4;
            float bi0 = bias2[mb + wr + d0];
            float bi1 = bias2[mb + wr + d0 + 1];
            float bi2 = bias2[mb + wr + d0 + 2];
            float bi3 = bias2[mb + wr + d0 + 3];
#pragma unroll
            for (int nt = 0; nt < 4; ++nt) {
                int n = nb + wc + nt * 16 + lm;
                half4 o;
                o[0] = (_Float16)((acc[mt][nt][0] + bi0) * sc);
                o[1] = (_Float16)((acc[mt][nt][1] + bi1) * sc);
                o[2] = (_Float16)((acc[mt][nt][2] + bi2) * sc);
                o[3] = (_Float16)((acc[mt][nt][3] + bi3) * sc);
                *(half4*)(dst + (size_t)n * 64 + d0) = o;
            }
        }
    } else {
        _Float16* dst = vb + bh * 64 * 1024;
#pragma unroll
        for (int mt = 0; mt < 4; ++mt)
#pragma unroll
            for (int reg = 0; reg < 4; ++reg) {
                int d = mt * 16 + lq * 4 + reg;
                float bi = bias2[mb + wr + d];
#pragma unroll
                for (int nt = 0; nt < 4; ++nt) {
                    int n = nb + wc + nt * 16 + lm;
                    dst[(size_t)d * 1024 + n] = (_Float16)(acc[mt][nt][reg] + bi);
                }
            }
    }
}

// Flash attention, fp16, S^T orientation, Mtile=128 (2 q-tiles per block share
// K/V staging, barriers, and kf fragments). R7 named-scalar prefetch. exp2
// softmax (q pre-scaled). XCD-locality: lin&63 = (b,h).
__global__ __launch_bounds__(256, 3) void k_attn(const _Float16* __restrict__ q2,
                                                 const _Float16* __restrict__ k2,
                                                 const _Float16* __restrict__ rel2,
                                                 const _Float16* __restrict__ vb,
                                                 float* __restrict__ out) {
    __shared__ __align__(16) char pool[45056];
    _Float16* kb_s = (_Float16*)pool;            // [64][136] = 17408 B (B-rows [k|q]; phase-0: A-rows)
    _Float16* v_s  = (_Float16*)(pool + 17408);  // [64][72]  =  9216 B
    _Float16* p_s  = (_Float16*)(pool + 26624);  // [128 m][72 n] = 18432 B (wave-private rows)
    int t = threadIdx.x;
    int lane = t & 63, w = t >> 6;
    int lm = lane & 15, lq = lane >> 4;
    int lin = blockIdx.x;
    int mt0 = lin >> 6;          // 0..7 (128 q-rows each)
    int bh_ = lin & 63;
    int h = bh_ & 7, b = bh_ >> 3;
    size_t bh = (size_t)b * 8 + h;
    const _Float16* q2b = q2 + bh * 1024 * 64;
    const _Float16* k2b = k2 + bh * 1024 * 64;
    const _Float16* relb = rel2 + (size_t)h * 1024 * 64;
    const _Float16* vbb = vb + bh * 64 * 1024;
    float* outb = out + bh * 64 * 1024 + mt0 * 128;

    int r = t >> 2, part = t & 3;
    const _Float16* ksrc = ((part < 2) ? (k2b + part * 32) : (q2b + (part - 2) * 32));
    int vc = (t & 3) * 16;
    const _Float16* vsrcb = vbb + (size_t)r * 1024 + vc;
    _Float16* kdst = kb_s + r * 136 + part * 32;
    _Float16* vdst = v_s + r * 72 + vc;

    // prefetch tile 0 into named scalar registers
    uint4 kc0, kc1, kc2, kc3, vv0, vv1;
    {
        const uint4* s_ = (const uint4*)(ksrc + (size_t)r * 64);
        kc0 = s_[0]; kc1 = s_[1]; kc2 = s_[2]; kc3 = s_[3];
        const uint4* v_ = (const uint4*)vsrcb;
        vv0 = v_[0]; vv1 = v_[1];
    }

    // Phase 0 round A: stage A-rows [q | rel] for m = mt0*128 + 0..63
    {
        int n = mt0 * 128 + r;
        const _Float16* src = (part < 2) ? (q2b + (size_t)n * 64 + part * 32)
                                         : (relb + (size_t)n * 64 + (part - 2) * 32);
        ((uint4*)kdst)[0] = ((const uint4*)src)[0];
        ((uint4*)kdst)[1] = ((const uint4*)src)[1];
        ((uint4*)kdst)[2] = ((const uint4*)src)[2];
        ((uint4*)kdst)[3] = ((const uint4*)src)[3];
    }
    __syncthreads();
    half8 ah0[4], ah1[4];
#pragma unroll
    for (int kk = 0; kk < 4; ++kk)
        ah0[kk] = *(half8*)&kb_s[(w * 16 + lm) * 136 + kk * 32 + lq * 8];
    __syncthreads();
    // Phase 0 round B: rows m = mt0*128 + 64..127
    {
        int n = mt0 * 128 + 64 + r;
        const _Float16* src = (part < 2) ? (q2b + (size_t)n * 64 + part * 32)
                                         : (relb + (size_t)n * 64 + (part - 2) * 32);
        ((uint4*)kdst)[0] = ((const uint4*)src)[0];
        ((uint4*)kdst)[1] = ((const uint4*)src)[1];
        ((uint4*)kdst)[2] = ((const uint4*)src)[2];
        ((uint4*)kdst)[3] = ((const uint4*)src)[3];
    }
    __syncthreads();
#pragma unroll
    for (int kk = 0; kk < 4; ++kk)
        ah1[kk] = *(half8*)&kb_s[(w * 16 + lm) * 136 + kk * 32 + lq * 8];
    __syncthreads();   // ah1 reads complete before first K ds_write

    f32x4 acco0[4], acco1[4];
#pragma unroll
    for (int i = 0; i < 4; ++i) { acco0[i] = {0.f, 0.f, 0.f, 0.f}; acco1[i] = {0.f, 0.f, 0.f, 0.f}; }
    float mrun0 = -3e38f, lrun0 = 0.f, mrun1 = -3e38f, lrun1 = 0.f;

    for (int kt = 0; kt < 16; ++kt) {
        ((uint4*)kdst)[0] = kc0;
        ((uint4*)kdst)[1] = kc1;
        ((uint4*)kdst)[2] = kc2;
        ((uint4*)kdst)[3] = kc3;
        ((uint4*)vdst)[0] = vv0;
        ((uint4*)vdst)[1] = vv1;
        __syncthreads();
        int nn = ((kt + 1) & 15) * 64;
        const uint4* s_ = (const uint4*)(ksrc + (size_t)(nn + r) * 64);
        uint4 kn0 = s_[0], kn1 = s_[1], kn2 = s_[2], kn3 = s_[3];
        const uint4* v_ = (const uint4*)(vsrcb + nn);
        uint4 vn0 = v_[0], vn1 = v_[1];
        // S^T: s0/s1[ct][reg] -> n = ct*16 + lq*4 + reg, m = w*16 + lm (+64 for s1)
        f32x4 s0[4], s1[4];
#pragma unroll
        for (int ct = 0; ct < 4; ++ct) { s0[ct] = {0.f, 0.f, 0.f, 0.f}; s1[ct] = {0.f, 0.f, 0.f, 0.f}; }
#pragma unroll
        for (int ct = 0; ct < 4; ++ct) {
            half8 kf[4];
#pragma unroll
            for (int kk = 0; kk < 4; ++kk)
                kf[kk] = *(half8*)&kb_s[(ct * 16 + lm) * 136 + kk * 32 + lq * 8];
#pragma unroll
            for (int kk = 0; kk < 4; ++kk) {
                s0[ct] = __builtin_amdgcn_mfma_f32_16x16x32_f16(kf[kk], ah0[kk], s0[ct], 0, 0, 0);
                s1[ct] = __builtin_amdgcn_mfma_f32_16x16x32_f16(kf[kk], ah1[kk], s1[ct], 0, 0, 0);
            }
        }
        // softmax tile 0 (per-lane column m; exp2 domain)
        {
            float mx = -3e38f;
#pragma unroll
            for (int ct = 0; ct < 4; ++ct)
#pragma unroll
                for (int reg = 0; reg < 4; ++reg) mx = fmaxf(mx, s0[ct][reg]);
            mx = fmaxf(mx, __shfl_xor(mx, 16));
            mx = fmaxf(mx, __shfl_xor(mx, 32));
            float mnew = fmaxf(mrun0, mx);
            float al_ = exp2f(mrun0 - mnew);
            float rs = 0.f;
#pragma unroll
            for (int ct = 0; ct < 4; ++ct) {
                float p0 = exp2f(s0[ct][0] - mnew);
                float p1 = exp2f(s0[ct][1] - mnew);
                float p2 = exp2f(s0[ct][2] - mnew);
                float p3 = exp2f(s0[ct][3] - mnew);
                rs += (p0 + p1) + (p2 + p3);
                half4 o; o[0] = (_Float16)p0; o[1] = (_Float16)p1; o[2] = (_Float16)p2; o[3] = (_Float16)p3;
                *(half4*)&p_s[(w * 16 + lm) * 72 + ct * 16 + lq * 4] = o;
            }
            rs += __shfl_xor(rs, 16);
            rs += __shfl_xor(rs, 32);
            lrun0 = lrun0 * al_ + rs;
            mrun0 = mnew;
#pragma unroll
            for (int dt = 0; dt < 4; ++dt) {
                acco0[dt][0] *= al_; acco0[dt][1] *= al_;
                acco0[dt][2] *= al_; acco0[dt][3] *= al_;
            }
        }
        // softmax tile 1
        {
            float mx = -3e38f;
#pragma unroll
            for (int ct = 0; ct < 4; ++ct)
#pragma unroll
                for (int reg = 0; reg < 4; ++reg) mx = fmaxf(mx, s1[ct][reg]);
            mx = fmaxf(mx, __shfl_xor(mx, 16));
            mx = fmaxf(mx, __shfl_xor(mx, 32));
            float mnew = fmaxf(mrun1, mx);
            float al_ = exp2f(mrun1 - mnew);
            float rs = 0.f;
#pragma unroll
            for (int ct = 0; ct < 4; ++ct) {
                float p0 = exp2f(s1[ct][0] - mnew);
                float p1 = exp2f(s1[ct][1] - mnew);
                float p2 = exp2f(s1[ct][2] - mnew);
                float p3 = exp2f(s1[ct][3] - mnew);
                rs += (p0 + p1) + (p2 + p3);
                half4 o; o[0] = (_Float16)p0; o[1] = (_Float16)p1; o[2] = (_Float16)p2; o[3] = (_Float16)p3;
                *(half4*)&p_s[(64 + w * 16 + lm) * 72 + ct * 16 + lq * 4] = o;
            }
            rs += __shfl_xor(rs, 16);
            rs += __shfl_xor(rs, 32);
            lrun1 = lrun1 * al_ + rs;
            mrun1 = mnew;
#pragma unroll
            for (int dt = 0; dt < 4; ++dt) {
                acco1[dt][0] *= al_; acco1[dt][1] *= al_;
                acco1[dt][2] *= al_; acco1[dt][3] *= al_;
            }
        }
        // PV for both tiles; v fragments shared
        half8 p0f[2], p1f[2];
#pragma unroll
        for (int ch = 0; ch < 2; ++ch) {
            p0f[ch] = *(half8*)&p_s[(w * 16 + lm) * 72 + ch * 32 + lq * 8];
            p1f[ch] = *(half8*)&p_s[(64 + w * 16 + lm) * 72 + ch * 32 + lq * 8];
        }
#pragma unroll
        for (int dt = 0; dt < 4; ++dt) {
            half8 vf0 = *(half8*)&v_s[(dt * 16 + lm) * 72 + lq * 8];
            half8 vf1 = *(half8*)&v_s[(dt * 16 + lm) * 72 + 32 + lq * 8];
            acco0[dt] = __builtin_amdgcn_mfma_f32_16x16x32_f16(vf0, p0f[0], acco0[dt], 0, 0, 0);
            acco0[dt] = __builtin_amdgcn_mfma_f32_16x16x32_f16(vf1, p0f[1], acco0[dt], 0, 0, 0);
            acco1[dt] = __builtin_amdgcn_mfma_f32_16x16x32_f16(vf0, p1f[0], acco1[dt], 0, 0, 0);
            acco1[dt] = __builtin_amdgcn_mfma_f32_16x16x32_f16(vf1, p1f[1], acco1[dt], 0, 0, 0);
        }
        __syncthreads();   // all reads of kb_s/v_s done before next ds_write
        kc0 = kn0; kc1 = kn1; kc2 = kn2; kc3 = kn3;
        vv0 = vn0; vv1 = vn1;
    }
    float li0 = 1.f / lrun0, li1 = 1.f / lrun1;
#pragma unroll
    for (int dt = 0; dt < 4; ++dt)
#pragma unroll
        for (int reg = 0; reg < 4; ++reg) {
            int d = dt * 16 + lq * 4 + reg;
            outb[(size_t)d * 1024 + w * 16 + lm] = acco0[dt][reg] * li0;
            outb[(size_t)d * 1024 + 64 + w * 16 + lm] = acco1[dt][reg] * li1;
        }
}

extern "C" void kernel_launch(void* const* d_in, const int* in_sizes, int n_in,
                              void* d_out, int out_size, void* d_ws, size_t ws_size,
                              hipStream_t stream) {
    const float* x     = (const float*)d_in[0];
    const float* Wq    = (const float*)d_in[1];
    const float* bq    = (const float*)d_in[2];
    const float* Wk    = (const float*)d_in[3];
    const float* bk    = (const float*)d_in[4];
    const float* Wv    = (const float*)d_in[5];
    const float* bv    = (const float*)d_in[6];
    const float* rel_h = (const float*)d_in[7];
    const float* rel_w = (const float*)d_in[8];
    char* ws = (char*)d_ws;
    _Float16* Wf   = (_Float16*)(ws);               //  1,572,864 B
    float* bias2   = (float*)(ws + 1572864);        //      6,144 B -> 1,579,008
    _Float16* xTf  = (_Float16*)(ws + 1579008);     //  8,388,608 B -> 9,967,616
    _Float16* q2   = (_Float16*)(ws + 9967616);     //  8,388,608 B -> 18,356,224
    _Float16* k2   = (_Float16*)(ws + 18356224);    //  8,388,608 B -> 26,744,832
    _Float16* vb   = (_Float16*)(ws + 26744832);    //  8,388,608 B -> 35,133,440
    _Float16* rel2 = (_Float16*)(ws + 35133440);    //  1,048,576 B -> 36,182,016
    float* out = (float*)d_out;

    hipLaunchKernelGGL(k_prep_all, dim3(1664),     dim3(256), 0, stream,
                       Wq, Wk, Wv, bq, bk, bv, x, rel_h, rel_w, Wf, bias2, xTf, rel2);
    hipLaunchKernelGGL(k_proj,     dim3(8, 12, 8), dim3(256), 0, stream, Wf, xTf, bias2, q2, k2, vb);
    hipLaunchKernelGGL(k_attn,     dim3(512),      dim3(256), 0, stream, q2, k2, rel2, vb, out);
}